// Round 3
// baseline (352.251 us; speedup 1.0000x reference)
//
#include <hip/hip_runtime.h>
#include <stdint.h>

#define N_NODES 6144
#define F_IN 512
#define NHEAD 4
#define FH 64
#define HF 256   // NHEAD*FH
#define NCLS 40
#define CAP 192
#define LRELU_ALPHA 0.2f

typedef __bf16 bf16x8 __attribute__((ext_vector_type(8)));
typedef float floatx4 __attribute__((ext_vector_type(4)));

__device__ __forceinline__ float b2f(uint16_t u){
    union { float f; uint32_t i; } x; x.i = ((uint32_t)u) << 16; return x.f;
}
__device__ __forceinline__ uint16_t f2b(float f){
    union { float f; uint32_t i; } x; x.f = f;
    uint32_t r = x.i + 0x7FFFu + ((x.i >> 16) & 1u);
    return (uint16_t)(r >> 16);
}

// ---------------- K0: fused prep ----------------
// blocks [0,3072):    x fp32 -> xh, xl bf16 (split precision)
// blocks [3072,3584): W [H,F,Fh] fp32 -> Wth/Wtl [HF, F] bf16 (transpose + split)
// blocks [3584,3624): Wo [256,40] fp32 -> Wot [40,256] fp32 (transpose)
__global__ void k_prep(const float* __restrict__ x, const float* __restrict__ W,
                       const float* __restrict__ Wo,
                       uint16_t* __restrict__ xh, uint16_t* __restrict__ xl,
                       uint16_t* __restrict__ Wth, uint16_t* __restrict__ Wtl,
                       float* __restrict__ Wot){
    int b = blockIdx.x, t = threadIdx.x;
    if (b < 3072){
        int idx = (b * 256 + t) * 4;
        float4 v = *reinterpret_cast<const float4*>(x + idx);
        ushort4 hi, lo;
        hi.x = f2b(v.x); lo.x = f2b(v.x - b2f(hi.x));
        hi.y = f2b(v.y); lo.y = f2b(v.y - b2f(hi.y));
        hi.z = f2b(v.z); lo.z = f2b(v.z - b2f(hi.z));
        hi.w = f2b(v.w); lo.w = f2b(v.w - b2f(hi.w));
        *reinterpret_cast<ushort4*>(xh + idx) = hi;
        *reinterpret_cast<ushort4*>(xl + idx) = lo;
    } else if (b < 3584){
        int idx = (b - 3072) * 256 + t;          // 0 .. 131071
        int c = idx >> 9, k = idx & 511;         // c = output row (h*64+f)
        float v = W[((c >> 6) << 15) + k * 64 + (c & 63)];
        uint16_t hi = f2b(v);
        Wth[idx] = hi;
        Wtl[idx] = f2b(v - b2f(hi));
    } else {
        int idx = (b - 3584) * 256 + t;          // 0 .. 10239
        int l = idx >> 8, k = idx & 255;
        Wot[idx] = Wo[k * NCLS + l];
    }
}

// ---------------- K1: dense fp32 adj row scan -> CSR-ish neighbor lists ----------------
__global__ void k_build_csr(const float* __restrict__ adj, int* __restrict__ cnt,
                            int* __restrict__ idxbuf){
    __shared__ int scnt;
    int i = blockIdx.x, t = threadIdx.x;
    if (t == 0) scnt = 0;
    __syncthreads();
    const float4* row = reinterpret_cast<const float4*>(adj + (size_t)i * N_NODES);
    int* out = idxbuf + (size_t)i * CAP;
    for (int q = t; q < N_NODES / 4; q += 256){
        float4 v = row[q];
        int j0 = q * 4;
        if (v.x != 0.f){ int p = atomicAdd(&scnt, 1); if (p < CAP) out[p] = j0;     }
        if (v.y != 0.f){ int p = atomicAdd(&scnt, 1); if (p < CAP) out[p] = j0 + 1; }
        if (v.z != 0.f){ int p = atomicAdd(&scnt, 1); if (p < CAP) out[p] = j0 + 2; }
        if (v.w != 0.f){ int p = atomicAdd(&scnt, 1); if (p < CAP) out[p] = j0 + 3; }
    }
    __syncthreads();
    if (t == 0) cnt[i] = scnt < CAP ? scnt : CAP;
}

// ---------------- K2: Wh1 = x @ Wcat  (split-bf16 MFMA: hi*hi + hi*lo + lo*hi) ----------------
// grid (192, 8), block 256. Block tile 32 rows x 32 cols; wave = one 16x16 tile.
__global__ void k_gemm1(const uint16_t* __restrict__ xh, const uint16_t* __restrict__ xl,
                        const uint16_t* __restrict__ Wth, const uint16_t* __restrict__ Wtl,
                        float* __restrict__ Wh1){
    int w = threadIdx.x >> 6, l = threadIdx.x & 63;
    int r0 = blockIdx.x * 32 + (w & 1) * 16;
    int c0 = blockIdx.y * 32 + (w >> 1) * 16;
    int m = l & 15, q = l >> 4;
    size_t aoff = (size_t)(r0 + m) * F_IN + q * 8;
    size_t boff = (size_t)(c0 + m) * F_IN + q * 8;
    const uint16_t* ahp = xh  + aoff;
    const uint16_t* alp = xl  + aoff;
    const uint16_t* bhp = Wth + boff;
    const uint16_t* blp = Wtl + boff;
    floatx4 acc = {0.f, 0.f, 0.f, 0.f};
    for (int k0 = 0; k0 < F_IN; k0 += 32){
        bf16x8 ah = *reinterpret_cast<const bf16x8*>(ahp + k0);
        bf16x8 al = *reinterpret_cast<const bf16x8*>(alp + k0);
        bf16x8 bh = *reinterpret_cast<const bf16x8*>(bhp + k0);
        bf16x8 bl = *reinterpret_cast<const bf16x8*>(blp + k0);
        acc = __builtin_amdgcn_mfma_f32_16x16x32_bf16(ah, bl, acc, 0, 0, 0);
        acc = __builtin_amdgcn_mfma_f32_16x16x32_bf16(al, bh, acc, 0, 0, 0);
        acc = __builtin_amdgcn_mfma_f32_16x16x32_bf16(ah, bh, acc, 0, 0, 0);
    }
    int col = c0 + m;
    int rowb = r0 + q * 4;
    #pragma unroll
    for (int r = 0; r < 4; r++)
        Wh1[(size_t)(rowb + r) * HF + col] = acc[r];
}

// ---------------- K3: f1[h,n], f2[h,n] = Wh1[n, h*64:...] . a1/a2 ----------------
__global__ void k_f12(const float* __restrict__ Wh1, const float* __restrict__ a1,
                      const float* __restrict__ a2, float* __restrict__ f1,
                      float* __restrict__ f2){
    int n = blockIdx.x;
    int h = threadIdx.x >> 6, l = threadIdx.x & 63;
    float w = Wh1[(size_t)n * HF + h * FH + l];
    float s1 = w * a1[h * FH + l];
    float s2 = w * a2[h * FH + l];
    for (int off = 32; off; off >>= 1){
        s1 += __shfl_xor(s1, off);
        s2 += __shfl_xor(s2, off);
    }
    if (l == 0){ f1[h * N_NODES + n] = s1; f2[h * N_NODES + n] = s2; }
}

// ---------------- K4: layer-1 sparse attention + ELU -> hcat [N, 256] ----------------
// grid (6144, 4), block 64 (one wave per (row, head))
__global__ void k_attn1(const int* __restrict__ cnt, const int* __restrict__ idxbuf,
                        const float* __restrict__ Wh1, const float* __restrict__ f1,
                        const float* __restrict__ f2, float* __restrict__ hcat){
    int i = blockIdx.x, h = blockIdx.y, l = threadIdx.x;
    int c = cnt[i];
    __shared__ int   sidx[CAP];
    __shared__ float sp[CAP];
    const int* src = idxbuf + (size_t)i * CAP;
    for (int e = l; e < c; e += 64) sidx[e] = src[e];
    __syncthreads();
    float f1i = f1[h * N_NODES + i];
    float mx = -1e30f;
    for (int e = l; e < c; e += 64){
        float s = f1i + f2[h * N_NODES + sidx[e]];
        s = s > 0.f ? s : LRELU_ALPHA * s;
        sp[e] = s;
        mx = fmaxf(mx, s);
    }
    for (int off = 32; off; off >>= 1) mx = fmaxf(mx, __shfl_xor(mx, off));
    __syncthreads();
    float ssum = 0.f;
    for (int e = l; e < c; e += 64){
        float p = __expf(sp[e] - mx);
        sp[e] = p;
        ssum += p;
    }
    for (int off = 32; off; off >>= 1) ssum += __shfl_xor(ssum, off);
    float inv = 1.f / ssum;
    __syncthreads();
    float acc = 0.f;
    const float* whb = Wh1 + h * FH + l;
    int e = 0;
    for (; e + 4 <= c; e += 4){
        int j0 = sidx[e], j1 = sidx[e+1], j2 = sidx[e+2], j3 = sidx[e+3];
        float v0 = whb[(size_t)j0 * HF];
        float v1 = whb[(size_t)j1 * HF];
        float v2 = whb[(size_t)j2 * HF];
        float v3 = whb[(size_t)j3 * HF];
        acc += sp[e]*v0 + sp[e+1]*v1 + sp[e+2]*v2 + sp[e+3]*v3;
    }
    for (; e < c; e++)
        acc += sp[e] * whb[(size_t)sidx[e] * HF];
    acc *= inv;
    float v = acc > 0.f ? acc : __expf(acc) - 1.f;   // ELU
    hcat[(size_t)i * HF + h * FH + l] = v;
}

// ---------------- K5: Wh2 = hcat @ Wo^T (+ fused f1o/f2o) ----------------
// grid 1536, block 256: wave w handles row n = blk*4+w; lane l = class (40 used)
__global__ void k_gemm2(const float* __restrict__ hcat, const float* __restrict__ Wot,
                        const float* __restrict__ ao1, const float* __restrict__ ao2,
                        float* __restrict__ Wh2, float* __restrict__ f1o,
                        float* __restrict__ f2o){
    int w = threadIdx.x >> 6, l = threadIdx.x & 63;
    int n = blockIdx.x * 4 + w;
    const float4* hr4 = reinterpret_cast<const float4*>(hcat + (size_t)n * HF);
    float acc = 0.f;
    if (l < NCLS){
        const float4* wr4 = reinterpret_cast<const float4*>(Wot + (size_t)l * HF);
        float a0 = 0.f, a1 = 0.f;
        #pragma unroll 8
        for (int k = 0; k < HF / 4; k += 2){
            float4 h0 = hr4[k],     w0 = wr4[k];
            float4 h1 = hr4[k + 1], w1 = wr4[k + 1];
            a0 += h0.x*w0.x + h0.y*w0.y + h0.z*w0.z + h0.w*w0.w;
            a1 += h1.x*w1.x + h1.y*w1.y + h1.z*w1.z + h1.w*w1.w;
        }
        acc = a0 + a1;
    }
    float t1 = l < NCLS ? acc * ao1[l] : 0.f;
    float t2 = l < NCLS ? acc * ao2[l] : 0.f;
    for (int off = 32; off; off >>= 1){
        t1 += __shfl_xor(t1, off);
        t2 += __shfl_xor(t2, off);
    }
    if (l < NCLS) Wh2[(size_t)n * NCLS + l] = acc;
    if (l == 0){ f1o[n] = t1; f2o[n] = t2; }
}

// ---------------- K6: layer-2 attention + ELU + log_softmax -> out fp32 ----------------
// grid 6144, block 64
__global__ void k_attn2(const int* __restrict__ cnt, const int* __restrict__ idxbuf,
                        const float* __restrict__ Wh2, const float* __restrict__ f1o,
                        const float* __restrict__ f2o, float* __restrict__ out){
    int i = blockIdx.x, l = threadIdx.x;
    int c = cnt[i];
    __shared__ int   sidx[CAP];
    __shared__ float sp[CAP];
    const int* src = idxbuf + (size_t)i * CAP;
    for (int e = l; e < c; e += 64) sidx[e] = src[e];
    __syncthreads();
    float f1i = f1o[i];
    float mx = -1e30f;
    for (int e = l; e < c; e += 64){
        float s = f1i + f2o[sidx[e]];
        s = s > 0.f ? s : LRELU_ALPHA * s;
        sp[e] = s;
        mx = fmaxf(mx, s);
    }
    for (int off = 32; off; off >>= 1) mx = fmaxf(mx, __shfl_xor(mx, off));
    __syncthreads();
    float ssum = 0.f;
    for (int e = l; e < c; e += 64){
        float p = __expf(sp[e] - mx);
        sp[e] = p;
        ssum += p;
    }
    for (int off = 32; off; off >>= 1) ssum += __shfl_xor(ssum, off);
    float inv = 1.f / ssum;
    __syncthreads();
    float acc = 0.f;
    if (l < NCLS){
        const float* wb = Wh2 + l;
        int e = 0;
        for (; e + 4 <= c; e += 4){
            int j0 = sidx[e], j1 = sidx[e+1], j2 = sidx[e+2], j3 = sidx[e+3];
            float v0 = wb[(size_t)j0 * NCLS];
            float v1 = wb[(size_t)j1 * NCLS];
            float v2 = wb[(size_t)j2 * NCLS];
            float v3 = wb[(size_t)j3 * NCLS];
            acc += sp[e]*v0 + sp[e+1]*v1 + sp[e+2]*v2 + sp[e+3]*v3;
        }
        for (; e < c; e++)
            acc += sp[e] * wb[(size_t)sidx[e] * NCLS];
        acc *= inv;
    }
    float o = (l < NCLS) ? (acc > 0.f ? acc : __expf(acc) - 1.f) : -1e30f;
    float m2 = o;
    for (int off = 32; off; off >>= 1) m2 = fmaxf(m2, __shfl_xor(m2, off));
    float ex = (l < NCLS) ? __expf(o - m2) : 0.f;
    for (int off = 32; off; off >>= 1) ex += __shfl_xor(ex, off);
    float res = o - m2 - logf(ex);
    if (l < NCLS) out[(size_t)i * NCLS + l] = res;
}

extern "C" void kernel_launch(void* const* d_in, const int* in_sizes, int n_in,
                              void* d_out, int out_size, void* d_ws, size_t ws_size,
                              hipStream_t stream) {
    const float* x   = (const float*)d_in[0];
    const float* adj = (const float*)d_in[1];
    const float* W   = (const float*)d_in[2];
    const float* a1  = (const float*)d_in[3];
    const float* a2  = (const float*)d_in[4];
    const float* Wo  = (const float*)d_in[5];
    const float* ao1 = (const float*)d_in[6];
    const float* ao2 = (const float*)d_in[7];
    float* out = (float*)d_out;

    char* ws = (char*)d_ws;
    int*      nbr_cnt = (int*)     (ws + 0);          //     24,576 B
    int*      nbr_idx = (int*)     (ws + 24576);      //  4,718,592 B
    uint16_t* xh      = (uint16_t*)(ws + 4743168);    //  6,291,456 B
    uint16_t* xl      = (uint16_t*)(ws + 11034624);   //  6,291,456 B
    uint16_t* Wth     = (uint16_t*)(ws + 17326080);   //    262,144 B
    uint16_t* Wtl     = (uint16_t*)(ws + 17588224);   //    262,144 B
    float*    Wot     = (float*)   (ws + 17850368);   //     40,960 B
    float*    Wh1     = (float*)   (ws + 17891328);   //  6,291,456 B
    float*    f1      = (float*)   (ws + 24182784);   //     98,304 B
    float*    f2      = (float*)   (ws + 24281088);   //     98,304 B
    float*    hcat    = (float*)   (ws + 24379392);   //  6,291,456 B
    float*    Wh2     = (float*)   (ws + 30670848);   //    983,040 B
    float*    f1o     = (float*)   (ws + 31653888);   //     24,576 B
    float*    f2o     = (float*)   (ws + 31678464);   //     24,576 B -> total ~31.7 MB

    hipLaunchKernelGGL(k_prep,      dim3(3624),       dim3(256), 0, stream, x, W, Wo, xh, xl, Wth, Wtl, Wot);
    hipLaunchKernelGGL(k_build_csr, dim3(6144),       dim3(256), 0, stream, adj, nbr_cnt, nbr_idx);
    hipLaunchKernelGGL(k_gemm1,     dim3(192, 8),     dim3(256), 0, stream, xh, xl, Wth, Wtl, Wh1);
    hipLaunchKernelGGL(k_f12,       dim3(6144),       dim3(256), 0, stream, Wh1, a1, a2, f1, f2);
    hipLaunchKernelGGL(k_attn1,     dim3(6144, 4),    dim3(64),  0, stream, nbr_cnt, nbr_idx, Wh1, f1, f2, hcat);
    hipLaunchKernelGGL(k_gemm2,     dim3(1536),       dim3(256), 0, stream, hcat, Wot, ao1, ao2, Wh2, f1o, f2o);
    hipLaunchKernelGGL(k_attn2,     dim3(6144),       dim3(64),  0, stream, nbr_cnt, nbr_idx, Wh2, f1o, f2o, out);
}

// Round 4
// 299.394 us; speedup vs baseline: 1.1765x; 1.1765x over previous
//
#include <hip/hip_runtime.h>
#include <stdint.h>

#define N_NODES 6144
#define F_IN 512
#define NHEAD 4
#define FH 64
#define HF 256   // NHEAD*FH
#define NCLS 40
#define NCLSP 48 // padded to 3x16 for MFMA
#define CAP 192
#define LRELU_ALPHA 0.2f

typedef __bf16 bf16x8 __attribute__((ext_vector_type(8)));
typedef float floatx4 __attribute__((ext_vector_type(4)));

__device__ __forceinline__ float b2f(uint16_t u){
    union { float f; uint32_t i; } x; x.i = ((uint32_t)u) << 16; return x.f;
}
__device__ __forceinline__ uint16_t f2b(float f){
    union { float f; uint32_t i; } x; x.f = f;
    uint32_t r = x.i + 0x7FFFu + ((x.i >> 16) & 1u);
    return (uint16_t)(r >> 16);
}

// Swizzled layout for MFMA A/B operands (16x16x32 frag):
//  elem (row tile rt, m=row%16, k-chunk kc, q=(k%32)/8, j=k%8)
//  -> halfword offset (rt*16+kc)*512 + (q*16+m)*8 + j
// so lane l=q*16+m reads 8 contiguous halfwords at ...*512 + l*8 (1 KB / wave-load).

// ---------------- K0: fused prep ----------------
// blocks [0,1536):     x fp32 -> xh/xl bf16 split, swizzled
// blocks [1536,1600):  W [H,F,Fh] fp32 -> Wth/Wtl bf16 split, transposed+swizzled
// blocks [1600,1648):  Wo [256,40] fp32 -> Woth/Wotl [48,256] bf16 split, transposed+padded
__global__ void k_prep(const float* __restrict__ x, const float* __restrict__ W,
                       const float* __restrict__ Wo,
                       uint16_t* __restrict__ xh, uint16_t* __restrict__ xl,
                       uint16_t* __restrict__ Wth, uint16_t* __restrict__ Wtl,
                       uint16_t* __restrict__ Woth, uint16_t* __restrict__ Wotl){
    int b = blockIdx.x, t = threadIdx.x;
    if (b < 1536){
        int T = b * 256 + t;                 // one thread per 8 elems of x
        int n = T >> 6, q8 = T & 63;
        const float4* xp = reinterpret_cast<const float4*>(x + (size_t)n * F_IN + q8 * 8);
        float4 v0 = xp[0], v1 = xp[1];
        int rt = n >> 4, m = n & 15, kc = q8 >> 2, q = q8 & 3;
        size_t off = ((size_t)(rt * 16 + kc) << 9) + (q * 16 + m) * 8;
        ushort4 h0, h1, l0, l1;
        h0.x = f2b(v0.x); l0.x = f2b(v0.x - b2f(h0.x));
        h0.y = f2b(v0.y); l0.y = f2b(v0.y - b2f(h0.y));
        h0.z = f2b(v0.z); l0.z = f2b(v0.z - b2f(h0.z));
        h0.w = f2b(v0.w); l0.w = f2b(v0.w - b2f(h0.w));
        h1.x = f2b(v1.x); l1.x = f2b(v1.x - b2f(h1.x));
        h1.y = f2b(v1.y); l1.y = f2b(v1.y - b2f(h1.y));
        h1.z = f2b(v1.z); l1.z = f2b(v1.z - b2f(h1.z));
        h1.w = f2b(v1.w); l1.w = f2b(v1.w - b2f(h1.w));
        *reinterpret_cast<ushort4*>(xh + off)     = h0;
        *reinterpret_cast<ushort4*>(xh + off + 4) = h1;
        *reinterpret_cast<ushort4*>(xl + off)     = l0;
        *reinterpret_cast<ushort4*>(xl + off + 4) = l1;
    } else if (b < 1600){
        int T = (b - 1536) * 256 + t;        // one thread per 8 k's of one Wt row
        int c = T >> 6, q8 = T & 63;         // c = concat col (h*64+fh)
        int h = c >> 6, f = c & 63, k0 = q8 * 8;
        int rt = c >> 4, m = c & 15, kc = q8 >> 2, q = q8 & 3;
        size_t off = ((size_t)(rt * 16 + kc) << 9) + (q * 16 + m) * 8;
        #pragma unroll
        for (int j = 0; j < 8; j++){
            float v = W[h * 32768 + (k0 + j) * 64 + f];
            uint16_t hi = f2b(v);
            Wth[off + j] = hi;
            Wtl[off + j] = f2b(v - b2f(hi));
        }
    } else {
        int T = (b - 1600) * 256 + t;        // 0..12287
        int c = T >> 8, k = T & 255;         // c = class (padded to 48), k
        float v = (c < NCLS) ? Wo[k * NCLS + c] : 0.f;
        uint16_t hi = f2b(v);
        Woth[c * HF + k] = hi;
        Wotl[c * HF + k] = f2b(v - b2f(hi));
    }
}

// ---------------- K1: dense fp32 adj row scan -> CSR-ish neighbor lists ----------------
__global__ void k_build_csr(const float* __restrict__ adj, int* __restrict__ cnt,
                            int* __restrict__ idxbuf){
    __shared__ int scnt;
    int i = blockIdx.x, t = threadIdx.x;
    if (t == 0) scnt = 0;
    __syncthreads();
    const float4* row = reinterpret_cast<const float4*>(adj + (size_t)i * N_NODES);
    int* out = idxbuf + (size_t)i * CAP;
    for (int q = t; q < N_NODES / 4; q += 256){
        float4 v = row[q];
        int j0 = q * 4;
        if (v.x != 0.f){ int p = atomicAdd(&scnt, 1); if (p < CAP) out[p] = j0;     }
        if (v.y != 0.f){ int p = atomicAdd(&scnt, 1); if (p < CAP) out[p] = j0 + 1; }
        if (v.z != 0.f){ int p = atomicAdd(&scnt, 1); if (p < CAP) out[p] = j0 + 2; }
        if (v.w != 0.f){ int p = atomicAdd(&scnt, 1); if (p < CAP) out[p] = j0 + 3; }
    }
    __syncthreads();
    if (t == 0) cnt[i] = scnt < CAP ? scnt : CAP;
}

// ---------------- K2: Wh1 = x @ Wcat (split-bf16 MFMA, swizzled operands) ----------------
// grid (96,4), block 256 = 4 waves; block tile 64x64, wave tile 32x32 (2x2 frags).
__global__ void k_gemm1(const uint16_t* __restrict__ xh, const uint16_t* __restrict__ xl,
                        const uint16_t* __restrict__ Wth, const uint16_t* __restrict__ Wtl,
                        float* __restrict__ Wh1){
    int w = threadIdx.x >> 6, l = threadIdx.x & 63;
    int rt0 = blockIdx.x * 4 + (w & 1) * 2;   // row tile (16-row units)
    int ct0 = blockIdx.y * 4 + (w >> 1) * 2;  // col tile
    const uint16_t* pah = xh  + ((size_t)rt0 << 13) + l * 8;  // rt0*16*512
    const uint16_t* pal = xl  + ((size_t)rt0 << 13) + l * 8;
    const uint16_t* pbh = Wth + ((size_t)ct0 << 13) + l * 8;
    const uint16_t* pbl = Wtl + ((size_t)ct0 << 13) + l * 8;
    floatx4 acc[2][2] = {};
    for (int kc = 0; kc < 16; kc++){
        int o0 = kc * 512, o1 = kc * 512 + 8192;
        bf16x8 a0h = *reinterpret_cast<const bf16x8*>(pah + o0);
        bf16x8 a0l = *reinterpret_cast<const bf16x8*>(pal + o0);
        bf16x8 a1h = *reinterpret_cast<const bf16x8*>(pah + o1);
        bf16x8 a1l = *reinterpret_cast<const bf16x8*>(pal + o1);
        bf16x8 b0h = *reinterpret_cast<const bf16x8*>(pbh + o0);
        bf16x8 b0l = *reinterpret_cast<const bf16x8*>(pbl + o0);
        bf16x8 b1h = *reinterpret_cast<const bf16x8*>(pbh + o1);
        bf16x8 b1l = *reinterpret_cast<const bf16x8*>(pbl + o1);
        acc[0][0] = __builtin_amdgcn_mfma_f32_16x16x32_bf16(a0h, b0l, acc[0][0], 0, 0, 0);
        acc[0][0] = __builtin_amdgcn_mfma_f32_16x16x32_bf16(a0l, b0h, acc[0][0], 0, 0, 0);
        acc[0][0] = __builtin_amdgcn_mfma_f32_16x16x32_bf16(a0h, b0h, acc[0][0], 0, 0, 0);
        acc[0][1] = __builtin_amdgcn_mfma_f32_16x16x32_bf16(a0h, b1l, acc[0][1], 0, 0, 0);
        acc[0][1] = __builtin_amdgcn_mfma_f32_16x16x32_bf16(a0l, b1h, acc[0][1], 0, 0, 0);
        acc[0][1] = __builtin_amdgcn_mfma_f32_16x16x32_bf16(a0h, b1h, acc[0][1], 0, 0, 0);
        acc[1][0] = __builtin_amdgcn_mfma_f32_16x16x32_bf16(a1h, b0l, acc[1][0], 0, 0, 0);
        acc[1][0] = __builtin_amdgcn_mfma_f32_16x16x32_bf16(a1l, b0h, acc[1][0], 0, 0, 0);
        acc[1][0] = __builtin_amdgcn_mfma_f32_16x16x32_bf16(a1h, b0h, acc[1][0], 0, 0, 0);
        acc[1][1] = __builtin_amdgcn_mfma_f32_16x16x32_bf16(a1h, b1l, acc[1][1], 0, 0, 0);
        acc[1][1] = __builtin_amdgcn_mfma_f32_16x16x32_bf16(a1l, b1h, acc[1][1], 0, 0, 0);
        acc[1][1] = __builtin_amdgcn_mfma_f32_16x16x32_bf16(a1h, b1h, acc[1][1], 0, 0, 0);
    }
    int m = l & 15, q = l >> 4;
    #pragma unroll
    for (int fr = 0; fr < 2; fr++){
        #pragma unroll
        for (int fc = 0; fc < 2; fc++){
            int col  = (ct0 + fc) * 16 + m;
            int rowb = (rt0 + fr) * 16 + q * 4;
            #pragma unroll
            for (int r = 0; r < 4; r++)
                Wh1[(size_t)(rowb + r) * HF + col] = acc[fr][fc][r];
        }
    }
}

// ---------------- K3: f1[h,n], f2[h,n] = Wh1[n, h*64:...] . a1/a2 ----------------
__global__ void k_f12(const float* __restrict__ Wh1, const float* __restrict__ a1,
                      const float* __restrict__ a2, float* __restrict__ f1,
                      float* __restrict__ f2){
    int n = blockIdx.x;
    int h = threadIdx.x >> 6, l = threadIdx.x & 63;
    float w = Wh1[(size_t)n * HF + h * FH + l];
    float s1 = w * a1[h * FH + l];
    float s2 = w * a2[h * FH + l];
    for (int off = 32; off; off >>= 1){
        s1 += __shfl_xor(s1, off);
        s2 += __shfl_xor(s2, off);
    }
    if (l == 0){ f1[h * N_NODES + n] = s1; f2[h * N_NODES + n] = s2; }
}

// ---------------- K4: layer-1 sparse attention + ELU -> hcat split bf16 ----------------
// grid 6144, block 256 (wave h = head h)
__global__ void k_attn1(const int* __restrict__ cnt, const int* __restrict__ idxbuf,
                        const float* __restrict__ Wh1, const float* __restrict__ f1,
                        const float* __restrict__ f2,
                        uint16_t* __restrict__ hch, uint16_t* __restrict__ hcl){
    int i = blockIdx.x, h = threadIdx.x >> 6, l = threadIdx.x & 63;
    int c = cnt[i];
    __shared__ int   sidx[CAP];
    __shared__ float sp[NHEAD][CAP];
    const int* src = idxbuf + (size_t)i * CAP;
    for (int e = threadIdx.x; e < c; e += 256) sidx[e] = src[e];
    __syncthreads();
    float f1i = f1[h * N_NODES + i];
    const float* f2h = f2 + h * N_NODES;
    float mx = -1e30f;
    for (int e = l; e < c; e += 64){
        float s = f1i + f2h[sidx[e]];
        s = s > 0.f ? s : LRELU_ALPHA * s;
        sp[h][e] = s;
        mx = fmaxf(mx, s);
    }
    for (int off = 32; off; off >>= 1) mx = fmaxf(mx, __shfl_xor(mx, off));
    float ssum = 0.f;
    for (int e = l; e < c; e += 64){
        float p = __expf(sp[h][e] - mx);
        sp[h][e] = p;
        ssum += p;
    }
    for (int off = 32; off; off >>= 1) ssum += __shfl_xor(ssum, off);
    float inv = 1.f / ssum;
    float acc = 0.f;
    const float* whb = Wh1 + h * FH + l;
    int e = 0;
    for (; e + 4 <= c; e += 4){
        int j0 = sidx[e], j1 = sidx[e+1], j2 = sidx[e+2], j3 = sidx[e+3];
        float v0 = whb[(size_t)j0 * HF];
        float v1 = whb[(size_t)j1 * HF];
        float v2 = whb[(size_t)j2 * HF];
        float v3 = whb[(size_t)j3 * HF];
        acc += sp[h][e]*v0 + sp[h][e+1]*v1 + sp[h][e+2]*v2 + sp[h][e+3]*v3;
    }
    for (; e < c; e++)
        acc += sp[h][e] * whb[(size_t)sidx[e] * HF];
    acc *= inv;
    float v = acc > 0.f ? acc : __expf(acc) - 1.f;   // ELU
    uint16_t hi = f2b(v);
    uint16_t lo = f2b(v - b2f(hi));
    size_t o = (size_t)i * HF + h * FH + l;
    hch[o] = hi;
    hcl[o] = lo;
}

// ---------------- K5: Wh2 = hcat @ Wo (split-bf16 MFMA, N padded to 48) ----------------
// grid (192,3), block 128 = 2 waves; wave tile 16 rows x 16 cols.
__global__ void k_gemm2(const uint16_t* __restrict__ hch, const uint16_t* __restrict__ hcl,
                        const uint16_t* __restrict__ Woth, const uint16_t* __restrict__ Wotl,
                        float* __restrict__ Wh2){
    int w = threadIdx.x >> 6, l = threadIdx.x & 63;
    int r0 = blockIdx.x * 32 + w * 16;
    int c0 = blockIdx.y * 16;
    int m = l & 15, q = l >> 4;
    const uint16_t* pah = hch  + (size_t)(r0 + m) * HF + q * 8;
    const uint16_t* pal = hcl  + (size_t)(r0 + m) * HF + q * 8;
    const uint16_t* pbh = Woth + (size_t)(c0 + m) * HF + q * 8;
    const uint16_t* pbl = Wotl + (size_t)(c0 + m) * HF + q * 8;
    floatx4 acc = {};
    for (int k0 = 0; k0 < HF; k0 += 32){
        bf16x8 ah = *reinterpret_cast<const bf16x8*>(pah + k0);
        bf16x8 al = *reinterpret_cast<const bf16x8*>(pal + k0);
        bf16x8 bh = *reinterpret_cast<const bf16x8*>(pbh + k0);
        bf16x8 bl = *reinterpret_cast<const bf16x8*>(pbl + k0);
        acc = __builtin_amdgcn_mfma_f32_16x16x32_bf16(ah, bl, acc, 0, 0, 0);
        acc = __builtin_amdgcn_mfma_f32_16x16x32_bf16(al, bh, acc, 0, 0, 0);
        acc = __builtin_amdgcn_mfma_f32_16x16x32_bf16(ah, bh, acc, 0, 0, 0);
    }
    int col = c0 + m;
    if (col < NCLS){
        int rowb = r0 + q * 4;
        #pragma unroll
        for (int r = 0; r < 4; r++)
            Wh2[(size_t)(rowb + r) * NCLS + col] = acc[r];
    }
}

// ---------------- K5b: f1o/f2o = Wh2 . ao1/ao2 ----------------
// grid 1536, block 256 (wave per row)
__global__ void k_f12o(const float* __restrict__ Wh2, const float* __restrict__ ao1,
                       const float* __restrict__ ao2, float* __restrict__ f1o,
                       float* __restrict__ f2o){
    int w = threadIdx.x >> 6, l = threadIdx.x & 63;
    int n = blockIdx.x * 4 + w;
    float t1 = 0.f, t2 = 0.f;
    if (l < NCLS){
        float v = Wh2[(size_t)n * NCLS + l];
        t1 = v * ao1[l];
        t2 = v * ao2[l];
    }
    for (int off = 32; off; off >>= 1){
        t1 += __shfl_xor(t1, off);
        t2 += __shfl_xor(t2, off);
    }
    if (l == 0){ f1o[n] = t1; f2o[n] = t2; }
}

// ---------------- K6: layer-2 attention + ELU + log_softmax -> out fp32 ----------------
// grid 6144, block 64
__global__ void k_attn2(const int* __restrict__ cnt, const int* __restrict__ idxbuf,
                        const float* __restrict__ Wh2, const float* __restrict__ f1o,
                        const float* __restrict__ f2o, float* __restrict__ out){
    int i = blockIdx.x, l = threadIdx.x;
    int c = cnt[i];
    __shared__ int   sidx[CAP];
    __shared__ float sp[CAP];
    const int* src = idxbuf + (size_t)i * CAP;
    for (int e = l; e < c; e += 64) sidx[e] = src[e];
    __syncthreads();
    float f1i = f1o[i];
    float mx = -1e30f;
    for (int e = l; e < c; e += 64){
        float s = f1i + f2o[sidx[e]];
        s = s > 0.f ? s : LRELU_ALPHA * s;
        sp[e] = s;
        mx = fmaxf(mx, s);
    }
    for (int off = 32; off; off >>= 1) mx = fmaxf(mx, __shfl_xor(mx, off));
    __syncthreads();
    float ssum = 0.f;
    for (int e = l; e < c; e += 64){
        float p = __expf(sp[e] - mx);
        sp[e] = p;
        ssum += p;
    }
    for (int off = 32; off; off >>= 1) ssum += __shfl_xor(ssum, off);
    float inv = 1.f / ssum;
    __syncthreads();
    float acc = 0.f;
    if (l < NCLS){
        const float* wb = Wh2 + l;
        int e = 0;
        for (; e + 4 <= c; e += 4){
            int j0 = sidx[e], j1 = sidx[e+1], j2 = sidx[e+2], j3 = sidx[e+3];
            float v0 = wb[(size_t)j0 * NCLS];
            float v1 = wb[(size_t)j1 * NCLS];
            float v2 = wb[(size_t)j2 * NCLS];
            float v3 = wb[(size_t)j3 * NCLS];
            acc += sp[e]*v0 + sp[e+1]*v1 + sp[e+2]*v2 + sp[e+3]*v3;
        }
        for (; e < c; e++)
            acc += sp[e] * wb[(size_t)sidx[e] * NCLS];
        acc *= inv;
    }
    float o = (l < NCLS) ? (acc > 0.f ? acc : __expf(acc) - 1.f) : -1e30f;
    float m2 = o;
    for (int off = 32; off; off >>= 1) m2 = fmaxf(m2, __shfl_xor(m2, off));
    float ex = (l < NCLS) ? __expf(o - m2) : 0.f;
    for (int off = 32; off; off >>= 1) ex += __shfl_xor(ex, off);
    float res = o - m2 - logf(ex);
    if (l < NCLS) out[(size_t)i * NCLS + l] = res;
}

extern "C" void kernel_launch(void* const* d_in, const int* in_sizes, int n_in,
                              void* d_out, int out_size, void* d_ws, size_t ws_size,
                              hipStream_t stream) {
    const float* x   = (const float*)d_in[0];
    const float* adj = (const float*)d_in[1];
    const float* W   = (const float*)d_in[2];
    const float* a1  = (const float*)d_in[3];
    const float* a2  = (const float*)d_in[4];
    const float* Wo  = (const float*)d_in[5];
    const float* ao1 = (const float*)d_in[6];
    const float* ao2 = (const float*)d_in[7];
    float* out = (float*)d_out;

    char* ws = (char*)d_ws;
    int*      nbr_cnt = (int*)     (ws + 0);          //     24,576 B
    int*      nbr_idx = (int*)     (ws + 24576);      //  4,718,592 B
    uint16_t* xh      = (uint16_t*)(ws + 4743168);    //  6,291,456 B
    uint16_t* xl      = (uint16_t*)(ws + 11034624);   //  6,291,456 B
    uint16_t* Wth     = (uint16_t*)(ws + 17326080);   //    262,144 B
    uint16_t* Wtl     = (uint16_t*)(ws + 17588224);   //    262,144 B
    uint16_t* Woth    = (uint16_t*)(ws + 17850368);   //     24,576 B
    uint16_t* Wotl    = (uint16_t*)(ws + 17874944);   //     24,576 B
    float*    Wh1     = (float*)   (ws + 17899520);   //  6,291,456 B
    float*    f1      = (float*)   (ws + 24190976);   //     98,304 B
    float*    f2      = (float*)   (ws + 24289280);   //     98,304 B
    uint16_t* hch     = (uint16_t*)(ws + 24387584);   //  3,145,728 B
    uint16_t* hcl     = (uint16_t*)(ws + 27533312);   //  3,145,728 B
    float*    Wh2     = (float*)   (ws + 30679040);   //    983,040 B
    float*    f1o     = (float*)   (ws + 31662080);   //     24,576 B
    float*    f2o     = (float*)   (ws + 31686656);   //     24,576 B -> total ~31.7 MB

    hipLaunchKernelGGL(k_prep,      dim3(1648),    dim3(256), 0, stream, x, W, Wo, xh, xl, Wth, Wtl, Woth, Wotl);
    hipLaunchKernelGGL(k_build_csr, dim3(6144),    dim3(256), 0, stream, adj, nbr_cnt, nbr_idx);
    hipLaunchKernelGGL(k_gemm1,     dim3(96, 4),   dim3(256), 0, stream, xh, xl, Wth, Wtl, Wh1);
    hipLaunchKernelGGL(k_f12,       dim3(6144),    dim3(256), 0, stream, Wh1, a1, a2, f1, f2);
    hipLaunchKernelGGL(k_attn1,     dim3(6144),    dim3(256), 0, stream, nbr_cnt, nbr_idx, Wh1, f1, f2, hch, hcl);
    hipLaunchKernelGGL(k_gemm2,     dim3(192, 3),  dim3(128), 0, stream, hch, hcl, Woth, Wotl, Wh2);
    hipLaunchKernelGGL(k_f12o,      dim3(1536),    dim3(256), 0, stream, Wh2, ao1, ao2, f1o, f2o);
    hipLaunchKernelGGL(k_attn2,     dim3(6144),    dim3(64),  0, stream, nbr_cnt, nbr_idx, Wh2, f1o, f2o, out);
}

// Round 5
// 287.741 us; speedup vs baseline: 1.2242x; 1.0405x over previous
//
#include <hip/hip_runtime.h>
#include <stdint.h>

#define N_NODES 6144
#define F_IN 512
#define NHEAD 4
#define FH 64
#define HF 256   // NHEAD*FH
#define NCLS 40
#define CAP 192
#define LRELU_ALPHA 0.2f

typedef __bf16 bf16x8 __attribute__((ext_vector_type(8)));
typedef float floatx4 __attribute__((ext_vector_type(4)));
typedef uint16_t u16x8 __attribute__((ext_vector_type(8)));

__device__ __forceinline__ float b2f(uint16_t u){
    union { float f; uint32_t i; } x; x.i = ((uint32_t)u) << 16; return x.f;
}
__device__ __forceinline__ uint16_t f2b(float f){
    union { float f; uint32_t i; } x; x.f = f;
    uint32_t r = x.i + 0x7FFFu + ((x.i >> 16) & 1u);
    return (uint16_t)(r >> 16);
}
__device__ __forceinline__ void cvt_split8(const float* __restrict__ s, bf16x8& hv, bf16x8& lv){
    union { u16x8 u; bf16x8 b; } H, L;
    #pragma unroll
    for (int j = 0; j < 8; j++){
        uint16_t hb = f2b(s[j]);
        H.u[j] = hb;
        L.u[j] = f2b(s[j] - b2f(hb));
    }
    hv = H.b; lv = L.b;
}

// Swizzled layout for MFMA B operands (16x16x32 frag):
//  halfword offset (coltile*16 + kc)*512 + lane*8, lane = q*16+m, elem j -> k = kc*32+q*8+j

// ---------------- K1: csr build + W/Wo prep ----------------
// blocks [0,6144):      adj row scan -> neighbor lists
// blocks [6144,6208):   W [H,F,Fh] fp32 -> Wth/Wtl bf16 split, transposed+swizzled
// blocks [6208,6256):   Wo [256,40] fp32 -> Woth/Wotl [48,256] bf16 split, transposed+padded
__global__ void k_csr_prep(const float* __restrict__ adj, const float* __restrict__ W,
                           const float* __restrict__ Wo,
                           int* __restrict__ cnt, int* __restrict__ idxbuf,
                           uint16_t* __restrict__ Wth, uint16_t* __restrict__ Wtl,
                           uint16_t* __restrict__ Woth, uint16_t* __restrict__ Wotl){
    __shared__ int scnt;
    int b = blockIdx.x, t = threadIdx.x;
    if (b < N_NODES){
        int i = b;
        if (t == 0) scnt = 0;
        __syncthreads();
        const float4* row = reinterpret_cast<const float4*>(adj + (size_t)i * N_NODES);
        int* out = idxbuf + (size_t)i * CAP;
        for (int q = t; q < N_NODES / 4; q += 256){
            float4 v = row[q];
            int j0 = q * 4;
            if (v.x != 0.f){ int p = atomicAdd(&scnt, 1); if (p < CAP) out[p] = j0;     }
            if (v.y != 0.f){ int p = atomicAdd(&scnt, 1); if (p < CAP) out[p] = j0 + 1; }
            if (v.z != 0.f){ int p = atomicAdd(&scnt, 1); if (p < CAP) out[p] = j0 + 2; }
            if (v.w != 0.f){ int p = atomicAdd(&scnt, 1); if (p < CAP) out[p] = j0 + 3; }
        }
        __syncthreads();
        if (t == 0) cnt[i] = scnt < CAP ? scnt : CAP;
    } else if (b < N_NODES + 64){
        int T = (b - N_NODES) * 256 + t;     // one thread per 8 k's of one Wt row
        int c = T >> 6, q8 = T & 63;         // c = concat col (h*64+fh)
        int h = c >> 6, f = c & 63, k0 = q8 * 8;
        int rt = c >> 4, m = c & 15, kc = q8 >> 2, q = q8 & 3;
        size_t off = ((size_t)(rt * 16 + kc) << 9) + (q * 16 + m) * 8;
        #pragma unroll
        for (int j = 0; j < 8; j++){
            float v = W[h * 32768 + (k0 + j) * 64 + f];
            uint16_t hi = f2b(v);
            Wth[off + j] = hi;
            Wtl[off + j] = f2b(v - b2f(hi));
        }
    } else {
        int T = (b - N_NODES - 64) * 256 + t; // 0..12287
        int c = T >> 8, k = T & 255;          // c = class (padded to 48), k
        float v = (c < NCLS) ? Wo[k * NCLS + c] : 0.f;
        uint16_t hi = f2b(v);
        Woth[c * HF + k] = hi;
        Wotl[c * HF + k] = f2b(v - b2f(hi));
    }
}

// ---------------- K2: Wh1b = bf16(x @ W_head), fused f1/f2 ----------------
// grid (96, 4=head), block 256; block tile 64 rows x 64 cols (one head).
// Wave tile 32x32 (2x2 frags); A read directly from fp32 x, split in-register.
__global__ void k_gemm1(const float* __restrict__ x,
                        const uint16_t* __restrict__ Wth, const uint16_t* __restrict__ Wtl,
                        const float* __restrict__ a1, const float* __restrict__ a2,
                        uint16_t* __restrict__ Wh1b, float* __restrict__ f1,
                        float* __restrict__ f2){
    __shared__ float sred[2][2][64];
    int w = threadIdx.x >> 6, l = threadIdx.x & 63;
    int h = blockIdx.y, bx = blockIdx.x;
    int m = l & 15, q = l >> 4;
    int rt0 = bx * 4 + (w & 1) * 2;           // row tile (16-row units)
    int ctl = (w >> 1) * 2;                   // local col tile within head
    const float* pa0 = x + (size_t)(rt0 * 16 + m) * F_IN + q * 8;
    const float* pa1 = pa0 + 16 * F_IN;
    const uint16_t* pb0h = Wth + ((size_t)(h * 4 + ctl) << 13) + l * 8;
    const uint16_t* pb0l = Wtl + ((size_t)(h * 4 + ctl) << 13) + l * 8;
    const uint16_t* pb1h = pb0h + 8192;
    const uint16_t* pb1l = pb0l + 8192;
    floatx4 acc[2][2] = {};
    for (int kc = 0; kc < 16; kc++){
        float av0[8], av1[8];
        *reinterpret_cast<float4*>(av0)     = *reinterpret_cast<const float4*>(pa0 + kc * 32);
        *reinterpret_cast<float4*>(av0 + 4) = *reinterpret_cast<const float4*>(pa0 + kc * 32 + 4);
        *reinterpret_cast<float4*>(av1)     = *reinterpret_cast<const float4*>(pa1 + kc * 32);
        *reinterpret_cast<float4*>(av1 + 4) = *reinterpret_cast<const float4*>(pa1 + kc * 32 + 4);
        bf16x8 b0h = *reinterpret_cast<const bf16x8*>(pb0h + kc * 512);
        bf16x8 b0l = *reinterpret_cast<const bf16x8*>(pb0l + kc * 512);
        bf16x8 b1h = *reinterpret_cast<const bf16x8*>(pb1h + kc * 512);
        bf16x8 b1l = *reinterpret_cast<const bf16x8*>(pb1l + kc * 512);
        bf16x8 a0h, a0l, a1h_, a1l_;
        cvt_split8(av0, a0h, a0l);
        cvt_split8(av1, a1h_, a1l_);
        acc[0][0] = __builtin_amdgcn_mfma_f32_16x16x32_bf16(a0h, b0l, acc[0][0], 0, 0, 0);
        acc[0][0] = __builtin_amdgcn_mfma_f32_16x16x32_bf16(a0l, b0h, acc[0][0], 0, 0, 0);
        acc[0][0] = __builtin_amdgcn_mfma_f32_16x16x32_bf16(a0h, b0h, acc[0][0], 0, 0, 0);
        acc[0][1] = __builtin_amdgcn_mfma_f32_16x16x32_bf16(a0h, b1l, acc[0][1], 0, 0, 0);
        acc[0][1] = __builtin_amdgcn_mfma_f32_16x16x32_bf16(a0l, b1h, acc[0][1], 0, 0, 0);
        acc[0][1] = __builtin_amdgcn_mfma_f32_16x16x32_bf16(a0h, b1h, acc[0][1], 0, 0, 0);
        acc[1][0] = __builtin_amdgcn_mfma_f32_16x16x32_bf16(a1h_, b0l, acc[1][0], 0, 0, 0);
        acc[1][0] = __builtin_amdgcn_mfma_f32_16x16x32_bf16(a1l_, b0h, acc[1][0], 0, 0, 0);
        acc[1][0] = __builtin_amdgcn_mfma_f32_16x16x32_bf16(a1h_, b0h, acc[1][0], 0, 0, 0);
        acc[1][1] = __builtin_amdgcn_mfma_f32_16x16x32_bf16(a1h_, b1l, acc[1][1], 0, 0, 0);
        acc[1][1] = __builtin_amdgcn_mfma_f32_16x16x32_bf16(a1l_, b1h, acc[1][1], 0, 0, 0);
        acc[1][1] = __builtin_amdgcn_mfma_f32_16x16x32_bf16(a1h_, b1h, acc[1][1], 0, 0, 0);
    }
    // write bf16 Wh1b
    #pragma unroll
    for (int fr = 0; fr < 2; fr++){
        #pragma unroll
        for (int fc = 0; fc < 2; fc++){
            int col = h * 64 + (ctl + fc) * 16 + m;
            int rowb = (rt0 + fr) * 16 + q * 4;
            #pragma unroll
            for (int r = 0; r < 4; r++)
                Wh1b[(size_t)(rowb + r) * HF + col] = f2b(acc[fr][fc][r]);
        }
    }
    // fused f1/f2: dot rows of acc with a1/a2 (exact fp32 path)
    float a1v0 = a1[h * FH + (ctl + 0) * 16 + m];
    float a1v1 = a1[h * FH + (ctl + 1) * 16 + m];
    float a2v0 = a2[h * FH + (ctl + 0) * 16 + m];
    float a2v1 = a2[h * FH + (ctl + 1) * 16 + m];
    #pragma unroll
    for (int fr = 0; fr < 2; fr++){
        #pragma unroll
        for (int r = 0; r < 4; r++){
            float s1 = acc[fr][0][r] * a1v0 + acc[fr][1][r] * a1v1;
            float s2 = acc[fr][0][r] * a2v0 + acc[fr][1][r] * a2v1;
            #pragma unroll
            for (int off = 1; off < 16; off <<= 1){
                s1 += __shfl_xor(s1, off);
                s2 += __shfl_xor(s2, off);
            }
            if (m == 0){
                int lr = ((w & 1) * 2 + fr) * 16 + q * 4 + r;
                sred[w >> 1][0][lr] = s1;
                sred[w >> 1][1][lr] = s2;
            }
        }
    }
    __syncthreads();
    if (threadIdx.x < 64){
        int n = bx * 64 + threadIdx.x;
        f1[h * N_NODES + n] = sred[0][0][threadIdx.x] + sred[1][0][threadIdx.x];
        f2[h * N_NODES + n] = sred[0][1][threadIdx.x] + sred[1][1][threadIdx.x];
    }
}

// ---------------- K3: layer-1 sparse attention + ELU -> hcat split bf16 ----------------
// grid 6144, block 256 (wave h = head h)
__global__ void k_attn1(const int* __restrict__ cnt, const int* __restrict__ idxbuf,
                        const uint16_t* __restrict__ Wh1b, const float* __restrict__ f1,
                        const float* __restrict__ f2,
                        uint16_t* __restrict__ hch, uint16_t* __restrict__ hcl){
    int i = blockIdx.x, h = threadIdx.x >> 6, l = threadIdx.x & 63;
    int c = cnt[i];
    __shared__ int   sidx[CAP];
    __shared__ float sp[NHEAD][CAP];
    const int* src = idxbuf + (size_t)i * CAP;
    for (int e = threadIdx.x; e < c; e += 256) sidx[e] = src[e];
    __syncthreads();
    float f1i = f1[h * N_NODES + i];
    const float* f2h = f2 + h * N_NODES;
    float mx = -1e30f;
    for (int e = l; e < c; e += 64){
        float s = f1i + f2h[sidx[e]];
        s = s > 0.f ? s : LRELU_ALPHA * s;
        sp[h][e] = s;
        mx = fmaxf(mx, s);
    }
    for (int off = 32; off; off >>= 1) mx = fmaxf(mx, __shfl_xor(mx, off));
    float ssum = 0.f;
    for (int e = l; e < c; e += 64){
        float p = __expf(sp[h][e] - mx);
        sp[h][e] = p;
        ssum += p;
    }
    for (int off = 32; off; off >>= 1) ssum += __shfl_xor(ssum, off);
    float inv = 1.f / ssum;
    float acc = 0.f;
    const uint16_t* whb = Wh1b + h * FH + l;
    int e = 0;
    for (; e + 4 <= c; e += 4){
        int j0 = sidx[e], j1 = sidx[e+1], j2 = sidx[e+2], j3 = sidx[e+3];
        float v0 = b2f(whb[(size_t)j0 * HF]);
        float v1 = b2f(whb[(size_t)j1 * HF]);
        float v2 = b2f(whb[(size_t)j2 * HF]);
        float v3 = b2f(whb[(size_t)j3 * HF]);
        acc += sp[h][e]*v0 + sp[h][e+1]*v1 + sp[h][e+2]*v2 + sp[h][e+3]*v3;
    }
    for (; e < c; e++)
        acc += sp[h][e] * b2f(whb[(size_t)sidx[e] * HF]);
    acc *= inv;
    float v = acc > 0.f ? acc : __expf(acc) - 1.f;   // ELU
    uint16_t hi = f2b(v);
    uint16_t lo = f2b(v - b2f(hi));
    size_t o = (size_t)i * HF + h * FH + l;
    hch[o] = hi;
    hcl[o] = lo;
}

// ---------------- K4: Wh2 = hcat @ Wo (split-bf16 MFMA, N padded to 48) ----------------
// grid (192,3), block 128 = 2 waves; wave tile 16 rows x 16 cols.
__global__ void k_gemm2(const uint16_t* __restrict__ hch, const uint16_t* __restrict__ hcl,
                        const uint16_t* __restrict__ Woth, const uint16_t* __restrict__ Wotl,
                        float* __restrict__ Wh2){
    int w = threadIdx.x >> 6, l = threadIdx.x & 63;
    int r0 = blockIdx.x * 32 + w * 16;
    int c0 = blockIdx.y * 16;
    int m = l & 15, q = l >> 4;
    const uint16_t* pah = hch  + (size_t)(r0 + m) * HF + q * 8;
    const uint16_t* pal = hcl  + (size_t)(r0 + m) * HF + q * 8;
    const uint16_t* pbh = Woth + (size_t)(c0 + m) * HF + q * 8;
    const uint16_t* pbl = Wotl + (size_t)(c0 + m) * HF + q * 8;
    floatx4 acc = {};
    for (int k0 = 0; k0 < HF; k0 += 32){
        bf16x8 ah = *reinterpret_cast<const bf16x8*>(pah + k0);
        bf16x8 al = *reinterpret_cast<const bf16x8*>(pal + k0);
        bf16x8 bh = *reinterpret_cast<const bf16x8*>(pbh + k0);
        bf16x8 bl = *reinterpret_cast<const bf16x8*>(pbl + k0);
        acc = __builtin_amdgcn_mfma_f32_16x16x32_bf16(ah, bl, acc, 0, 0, 0);
        acc = __builtin_amdgcn_mfma_f32_16x16x32_bf16(al, bh, acc, 0, 0, 0);
        acc = __builtin_amdgcn_mfma_f32_16x16x32_bf16(ah, bh, acc, 0, 0, 0);
    }
    int col = c0 + m;
    if (col < NCLS){
        int rowb = r0 + q * 4;
        #pragma unroll
        for (int r = 0; r < 4; r++)
            Wh2[(size_t)(rowb + r) * NCLS + col] = acc[r];
    }
}

// ---------------- K5: f1o/f2o = Wh2 . ao1/ao2 ----------------
__global__ void k_f12o(const float* __restrict__ Wh2, const float* __restrict__ ao1,
                       const float* __restrict__ ao2, float* __restrict__ f1o,
                       float* __restrict__ f2o){
    int w = threadIdx.x >> 6, l = threadIdx.x & 63;
    int n = blockIdx.x * 4 + w;
    float t1 = 0.f, t2 = 0.f;
    if (l < NCLS){
        float v = Wh2[(size_t)n * NCLS + l];
        t1 = v * ao1[l];
        t2 = v * ao2[l];
    }
    for (int off = 32; off; off >>= 1){
        t1 += __shfl_xor(t1, off);
        t2 += __shfl_xor(t2, off);
    }
    if (l == 0){ f1o[n] = t1; f2o[n] = t2; }
}

// ---------------- K6: layer-2 attention + ELU + log_softmax -> out fp32 ----------------
// grid 6144, block 64
__global__ void k_attn2(const int* __restrict__ cnt, const int* __restrict__ idxbuf,
                        const float* __restrict__ Wh2, const float* __restrict__ f1o,
                        const float* __restrict__ f2o, float* __restrict__ out){
    int i = blockIdx.x, l = threadIdx.x;
    int c = cnt[i];
    __shared__ int   sidx[CAP];
    __shared__ float sp[CAP];
    const int* src = idxbuf + (size_t)i * CAP;
    for (int e = l; e < c; e += 64) sidx[e] = src[e];
    __syncthreads();
    float f1i = f1o[i];
    float mx = -1e30f;
    for (int e = l; e < c; e += 64){
        float s = f1i + f2o[sidx[e]];
        s = s > 0.f ? s : LRELU_ALPHA * s;
        sp[e] = s;
        mx = fmaxf(mx, s);
    }
    for (int off = 32; off; off >>= 1) mx = fmaxf(mx, __shfl_xor(mx, off));
    __syncthreads();
    float ssum = 0.f;
    for (int e = l; e < c; e += 64){
        float p = __expf(sp[e] - mx);
        sp[e] = p;
        ssum += p;
    }
    for (int off = 32; off; off >>= 1) ssum += __shfl_xor(ssum, off);
    float inv = 1.f / ssum;
    __syncthreads();
    float acc = 0.f;
    if (l < NCLS){
        const float* wb = Wh2 + l;
        int e = 0;
        for (; e + 4 <= c; e += 4){
            int j0 = sidx[e], j1 = sidx[e+1], j2 = sidx[e+2], j3 = sidx[e+3];
            float v0 = wb[(size_t)j0 * NCLS];
            float v1 = wb[(size_t)j1 * NCLS];
            float v2 = wb[(size_t)j2 * NCLS];
            float v3 = wb[(size_t)j3 * NCLS];
            acc += sp[e]*v0 + sp[e+1]*v1 + sp[e+2]*v2 + sp[e+3]*v3;
        }
        for (; e < c; e++)
            acc += sp[e] * wb[(size_t)sidx[e] * NCLS];
        acc *= inv;
    }
    float o = (l < NCLS) ? (acc > 0.f ? acc : __expf(acc) - 1.f) : -1e30f;
    float m2 = o;
    for (int off = 32; off; off >>= 1) m2 = fmaxf(m2, __shfl_xor(m2, off));
    float ex = (l < NCLS) ? __expf(o - m2) : 0.f;
    for (int off = 32; off; off >>= 1) ex += __shfl_xor(ex, off);
    float res = o - m2 - logf(ex);
    if (l < NCLS) out[(size_t)i * NCLS + l] = res;
}

extern "C" void kernel_launch(void* const* d_in, const int* in_sizes, int n_in,
                              void* d_out, int out_size, void* d_ws, size_t ws_size,
                              hipStream_t stream) {
    const float* x   = (const float*)d_in[0];
    const float* adj = (const float*)d_in[1];
    const float* W   = (const float*)d_in[2];
    const float* a1  = (const float*)d_in[3];
    const float* a2  = (const float*)d_in[4];
    const float* Wo  = (const float*)d_in[5];
    const float* ao1 = (const float*)d_in[6];
    const float* ao2 = (const float*)d_in[7];
    float* out = (float*)d_out;

    char* ws = (char*)d_ws;
    int*      nbr_cnt = (int*)     (ws + 0);          //     24,576 B
    int*      nbr_idx = (int*)     (ws + 24576);      //  4,718,592 B
    uint16_t* Wth     = (uint16_t*)(ws + 4743168);    //    262,144 B
    uint16_t* Wtl     = (uint16_t*)(ws + 5005312);    //    262,144 B
    uint16_t* Woth    = (uint16_t*)(ws + 5267456);    //     24,576 B
    uint16_t* Wotl    = (uint16_t*)(ws + 5292032);    //     24,576 B
    uint16_t* Wh1b    = (uint16_t*)(ws + 5316608);    //  3,145,728 B
    float*    f1      = (float*)   (ws + 8462336);    //     98,304 B
    float*    f2      = (float*)   (ws + 8560640);    //     98,304 B
    uint16_t* hch     = (uint16_t*)(ws + 8658944);    //  3,145,728 B
    uint16_t* hcl     = (uint16_t*)(ws + 11804672);   //  3,145,728 B
    float*    Wh2     = (float*)   (ws + 14950400);   //    983,040 B
    float*    f1o     = (float*)   (ws + 15933440);   //     24,576 B
    float*    f2o     = (float*)   (ws + 15958016);   //     24,576 B -> total ~16 MB

    hipLaunchKernelGGL(k_csr_prep, dim3(6256),   dim3(256), 0, stream, adj, W, Wo,
                       nbr_cnt, nbr_idx, Wth, Wtl, Woth, Wotl);
    hipLaunchKernelGGL(k_gemm1,    dim3(96, 4),  dim3(256), 0, stream, x, Wth, Wtl,
                       a1, a2, Wh1b, f1, f2);
    hipLaunchKernelGGL(k_attn1,    dim3(6144),   dim3(256), 0, stream, nbr_cnt, nbr_idx,
                       Wh1b, f1, f2, hch, hcl);
    hipLaunchKernelGGL(k_gemm2,    dim3(192, 3), dim3(128), 0, stream, hch, hcl, Woth, Wotl, Wh2);
    hipLaunchKernelGGL(k_f12o,     dim3(1536),   dim3(256), 0, stream, Wh2, ao1, ao2, f1o, f2o);
    hipLaunchKernelGGL(k_attn2,    dim3(6144),   dim3(64),  0, stream, nbr_cnt, nbr_idx,
                       Wh2, f1o, f2o, out);
}

// Round 6
// 268.820 us; speedup vs baseline: 1.3104x; 1.0704x over previous
//
#include <hip/hip_runtime.h>
#include <stdint.h>

#define N_NODES 6144
#define F_IN 512
#define NHEAD 4
#define FH 64
#define HF 256   // NHEAD*FH
#define NCLS 40
#define CAP 192
#define LRELU_ALPHA 0.2f

typedef __bf16 bf16x8 __attribute__((ext_vector_type(8)));
typedef float floatx4 __attribute__((ext_vector_type(4)));
typedef uint16_t u16x8 __attribute__((ext_vector_type(8)));

__device__ __forceinline__ float b2f(uint16_t u){
    union { float f; uint32_t i; } x; x.i = ((uint32_t)u) << 16; return x.f;
}
__device__ __forceinline__ uint16_t f2b(float f){
    union { float f; uint32_t i; } x; x.f = f;
    uint32_t r = x.i + 0x7FFFu + ((x.i >> 16) & 1u);
    return (uint16_t)(r >> 16);
}
__device__ __forceinline__ void cvt_split8(const float* __restrict__ s, bf16x8& hv, bf16x8& lv){
    union { u16x8 u; bf16x8 b; } H, L;
    #pragma unroll
    for (int j = 0; j < 8; j++){
        uint16_t hb = f2b(s[j]);
        H.u[j] = hb;
        L.u[j] = f2b(s[j] - b2f(hb));
    }
    hv = H.b; lv = L.b;
}

// ================= Kernel A =================
// blocks [0,384):     gemm1: Wh1b = bf16(x @ W_head) + fused f1/f2  (b = bx*4 + h)
// blocks [384,432):   Wo prep -> Woth/Wotl [48,256] bf16 split transposed+padded
// block  432:         zero f1o/f2o
// blocks [433,6577):  adj row scan -> CSR neighbor lists
// gemm1 blocks dispatched first so their MFMA/VALU work overlaps the
// memory-bound adj scan (separate pipes co-schedule; m114).
__global__ void k_A(const float* __restrict__ adj, const float* __restrict__ x,
                    const float* __restrict__ W, const float* __restrict__ Wo,
                    const float* __restrict__ a1, const float* __restrict__ a2,
                    int* __restrict__ cnt, int* __restrict__ idxbuf,
                    uint16_t* __restrict__ Woth, uint16_t* __restrict__ Wotl,
                    uint16_t* __restrict__ Wh1b, float* __restrict__ f1,
                    float* __restrict__ f2, float* __restrict__ f1o,
                    float* __restrict__ f2o){
    int b = blockIdx.x, t = threadIdx.x;
    if (b < 384){
        // ---- gemm1 ----
        __shared__ float sred[2][2][64];
        int w = t >> 6, l = t & 63;
        int bx = b >> 2, h = b & 3;
        int m = l & 15, q = l >> 4;
        int rt0 = bx * 4 + (w & 1) * 2;           // row tile (16-row units)
        int ctl = (w >> 1) * 2;                   // local col tile within head
        const float* pa0 = x + (size_t)(rt0 * 16 + m) * F_IN + q * 8;
        const float* pa1 = pa0 + 16 * F_IN;
        // W[h][k][f]: base for this wave's B fragments
        const float* pb = W + h * 32768 + q * 8 * 64 + ctl * 16 + m;
        floatx4 acc[2][2] = {};
        for (int kc = 0; kc < 16; kc++){
            float av0[8], av1[8], bv0[8], bv1[8];
            *reinterpret_cast<float4*>(av0)     = *reinterpret_cast<const float4*>(pa0 + kc * 32);
            *reinterpret_cast<float4*>(av0 + 4) = *reinterpret_cast<const float4*>(pa0 + kc * 32 + 4);
            *reinterpret_cast<float4*>(av1)     = *reinterpret_cast<const float4*>(pa1 + kc * 32);
            *reinterpret_cast<float4*>(av1 + 4) = *reinterpret_cast<const float4*>(pa1 + kc * 32 + 4);
            const float* pbk = pb + kc * 2048;
            #pragma unroll
            for (int j = 0; j < 8; j++){
                bv0[j] = pbk[j * 64];
                bv1[j] = pbk[j * 64 + 16];
            }
            bf16x8 a0h, a0l, a1h_, a1l_, b0h, b0l, b1h, b1l;
            cvt_split8(av0, a0h, a0l);
            cvt_split8(av1, a1h_, a1l_);
            cvt_split8(bv0, b0h, b0l);
            cvt_split8(bv1, b1h, b1l);
            acc[0][0] = __builtin_amdgcn_mfma_f32_16x16x32_bf16(a0h, b0l, acc[0][0], 0, 0, 0);
            acc[0][0] = __builtin_amdgcn_mfma_f32_16x16x32_bf16(a0l, b0h, acc[0][0], 0, 0, 0);
            acc[0][0] = __builtin_amdgcn_mfma_f32_16x16x32_bf16(a0h, b0h, acc[0][0], 0, 0, 0);
            acc[0][1] = __builtin_amdgcn_mfma_f32_16x16x32_bf16(a0h, b1l, acc[0][1], 0, 0, 0);
            acc[0][1] = __builtin_amdgcn_mfma_f32_16x16x32_bf16(a0l, b1h, acc[0][1], 0, 0, 0);
            acc[0][1] = __builtin_amdgcn_mfma_f32_16x16x32_bf16(a0h, b1h, acc[0][1], 0, 0, 0);
            acc[1][0] = __builtin_amdgcn_mfma_f32_16x16x32_bf16(a1h_, b0l, acc[1][0], 0, 0, 0);
            acc[1][0] = __builtin_amdgcn_mfma_f32_16x16x32_bf16(a1l_, b0h, acc[1][0], 0, 0, 0);
            acc[1][0] = __builtin_amdgcn_mfma_f32_16x16x32_bf16(a1h_, b0h, acc[1][0], 0, 0, 0);
            acc[1][1] = __builtin_amdgcn_mfma_f32_16x16x32_bf16(a1h_, b1l, acc[1][1], 0, 0, 0);
            acc[1][1] = __builtin_amdgcn_mfma_f32_16x16x32_bf16(a1l_, b1h, acc[1][1], 0, 0, 0);
            acc[1][1] = __builtin_amdgcn_mfma_f32_16x16x32_bf16(a1h_, b1h, acc[1][1], 0, 0, 0);
        }
        // write bf16 Wh1b
        #pragma unroll
        for (int fr = 0; fr < 2; fr++){
            #pragma unroll
            for (int fc = 0; fc < 2; fc++){
                int col = h * 64 + (ctl + fc) * 16 + m;
                int rowb = (rt0 + fr) * 16 + q * 4;
                #pragma unroll
                for (int r = 0; r < 4; r++)
                    Wh1b[(size_t)(rowb + r) * HF + col] = f2b(acc[fr][fc][r]);
            }
        }
        // fused f1/f2 (exact fp32 path)
        float a1v0 = a1[h * FH + (ctl + 0) * 16 + m];
        float a1v1 = a1[h * FH + (ctl + 1) * 16 + m];
        float a2v0 = a2[h * FH + (ctl + 0) * 16 + m];
        float a2v1 = a2[h * FH + (ctl + 1) * 16 + m];
        #pragma unroll
        for (int fr = 0; fr < 2; fr++){
            #pragma unroll
            for (int r = 0; r < 4; r++){
                float s1 = acc[fr][0][r] * a1v0 + acc[fr][1][r] * a1v1;
                float s2 = acc[fr][0][r] * a2v0 + acc[fr][1][r] * a2v1;
                #pragma unroll
                for (int off = 1; off < 16; off <<= 1){
                    s1 += __shfl_xor(s1, off);
                    s2 += __shfl_xor(s2, off);
                }
                if (m == 0){
                    int lr = ((w & 1) * 2 + fr) * 16 + q * 4 + r;
                    sred[w >> 1][0][lr] = s1;
                    sred[w >> 1][1][lr] = s2;
                }
            }
        }
        __syncthreads();
        if (t < 64){
            int n = bx * 64 + t;
            f1[h * N_NODES + n] = sred[0][0][t] + sred[1][0][t];
            f2[h * N_NODES + n] = sred[0][1][t] + sred[1][1][t];
        }
    } else if (b < 432){
        int T = (b - 384) * 256 + t;          // 0..12287
        int c = T >> 8, k = T & 255;          // c = class (padded to 48), k
        float v = (c < NCLS) ? Wo[k * NCLS + c] : 0.f;
        uint16_t hi = f2b(v);
        Woth[c * HF + k] = hi;
        Wotl[c * HF + k] = f2b(v - b2f(hi));
    } else if (b == 432){
        for (int i = t; i < N_NODES; i += 256){ f1o[i] = 0.f; f2o[i] = 0.f; }
    } else {
        // ---- adj row scan ----
        __shared__ int scnt;
        int i = b - 433;
        if (t == 0) scnt = 0;
        __syncthreads();
        const float4* row = reinterpret_cast<const float4*>(adj + (size_t)i * N_NODES);
        int* out = idxbuf + (size_t)i * CAP;
        for (int q = t; q < N_NODES / 4; q += 256){
            float4 v = row[q];
            int j0 = q * 4;
            if (v.x != 0.f){ int p = atomicAdd(&scnt, 1); if (p < CAP) out[p] = j0;     }
            if (v.y != 0.f){ int p = atomicAdd(&scnt, 1); if (p < CAP) out[p] = j0 + 1; }
            if (v.z != 0.f){ int p = atomicAdd(&scnt, 1); if (p < CAP) out[p] = j0 + 2; }
            if (v.w != 0.f){ int p = atomicAdd(&scnt, 1); if (p < CAP) out[p] = j0 + 3; }
        }
        __syncthreads();
        if (t == 0) cnt[i] = scnt < CAP ? scnt : CAP;
    }
}

// ================= Kernel B: layer-1 sparse attention + ELU -> hcat split bf16 =============
// grid 6144, block 256 (wave h = head h)
__global__ void k_attn1(const int* __restrict__ cnt, const int* __restrict__ idxbuf,
                        const uint16_t* __restrict__ Wh1b, const float* __restrict__ f1,
                        const float* __restrict__ f2,
                        uint16_t* __restrict__ hch, uint16_t* __restrict__ hcl){
    int i = blockIdx.x, h = threadIdx.x >> 6, l = threadIdx.x & 63;
    int c = cnt[i];
    __shared__ int   sidx[CAP];
    __shared__ float sp[NHEAD][CAP];
    const int* src = idxbuf + (size_t)i * CAP;
    for (int e = threadIdx.x; e < c; e += 256) sidx[e] = src[e];
    __syncthreads();
    float f1i = f1[h * N_NODES + i];
    const float* f2h = f2 + h * N_NODES;
    float mx = -1e30f;
    for (int e = l; e < c; e += 64){
        float s = f1i + f2h[sidx[e]];
        s = s > 0.f ? s : LRELU_ALPHA * s;
        sp[h][e] = s;
        mx = fmaxf(mx, s);
    }
    for (int off = 32; off; off >>= 1) mx = fmaxf(mx, __shfl_xor(mx, off));
    float ssum = 0.f;
    for (int e = l; e < c; e += 64){
        float p = __expf(sp[h][e] - mx);
        sp[h][e] = p;
        ssum += p;
    }
    for (int off = 32; off; off >>= 1) ssum += __shfl_xor(ssum, off);
    float inv = 1.f / ssum;
    float acc = 0.f;
    const uint16_t* whb = Wh1b + h * FH + l;
    int e = 0;
    for (; e + 4 <= c; e += 4){
        int j0 = sidx[e], j1 = sidx[e+1], j2 = sidx[e+2], j3 = sidx[e+3];
        float v0 = b2f(whb[(size_t)j0 * HF]);
        float v1 = b2f(whb[(size_t)j1 * HF]);
        float v2 = b2f(whb[(size_t)j2 * HF]);
        float v3 = b2f(whb[(size_t)j3 * HF]);
        acc += sp[h][e]*v0 + sp[h][e+1]*v1 + sp[h][e+2]*v2 + sp[h][e+3]*v3;
    }
    for (; e < c; e++)
        acc += sp[h][e] * b2f(whb[(size_t)sidx[e] * HF]);
    acc *= inv;
    float v = acc > 0.f ? acc : __expf(acc) - 1.f;   // ELU
    uint16_t hi = f2b(v);
    uint16_t lo = f2b(v - b2f(hi));
    size_t o = (size_t)i * HF + h * FH + l;
    hch[o] = hi;
    hcl[o] = lo;
}

// ========== Kernel C: Wh2 = hcat @ Wo (split-bf16 MFMA) + fused f1o/f2o (atomics) ==========
// grid (192,3), block 128 = 2 waves; wave tile 16 rows x 16 cols.
__global__ void k_gemm2(const uint16_t* __restrict__ hch, const uint16_t* __restrict__ hcl,
                        const uint16_t* __restrict__ Woth, const uint16_t* __restrict__ Wotl,
                        const float* __restrict__ ao1, const float* __restrict__ ao2,
                        float* __restrict__ Wh2, float* __restrict__ f1o,
                        float* __restrict__ f2o){
    int w = threadIdx.x >> 6, l = threadIdx.x & 63;
    int r0 = blockIdx.x * 32 + w * 16;
    int c0 = blockIdx.y * 16;
    int m = l & 15, q = l >> 4;
    const uint16_t* pah = hch  + (size_t)(r0 + m) * HF + q * 8;
    const uint16_t* pal = hcl  + (size_t)(r0 + m) * HF + q * 8;
    const uint16_t* pbh = Woth + (size_t)(c0 + m) * HF + q * 8;
    const uint16_t* pbl = Wotl + (size_t)(c0 + m) * HF + q * 8;
    floatx4 acc = {};
    for (int k0 = 0; k0 < HF; k0 += 32){
        bf16x8 ah = *reinterpret_cast<const bf16x8*>(pah + k0);
        bf16x8 al = *reinterpret_cast<const bf16x8*>(pal + k0);
        bf16x8 bh = *reinterpret_cast<const bf16x8*>(pbh + k0);
        bf16x8 bl = *reinterpret_cast<const bf16x8*>(pbl + k0);
        acc = __builtin_amdgcn_mfma_f32_16x16x32_bf16(ah, bl, acc, 0, 0, 0);
        acc = __builtin_amdgcn_mfma_f32_16x16x32_bf16(al, bh, acc, 0, 0, 0);
        acc = __builtin_amdgcn_mfma_f32_16x16x32_bf16(ah, bh, acc, 0, 0, 0);
    }
    int col = c0 + m;
    bool valid = col < NCLS;
    if (valid){
        int rowb = r0 + q * 4;
        #pragma unroll
        for (int r = 0; r < 4; r++)
            Wh2[(size_t)(rowb + r) * NCLS + col] = acc[r];
    }
    float w1 = valid ? ao1[col] : 0.f;
    float w2 = valid ? ao2[col] : 0.f;
    #pragma unroll
    for (int r = 0; r < 4; r++){
        float s1 = acc[r] * w1;
        float s2 = acc[r] * w2;
        #pragma unroll
        for (int off = 1; off < 16; off <<= 1){
            s1 += __shfl_xor(s1, off);
            s2 += __shfl_xor(s2, off);
        }
        if (m == 0){
            atomicAdd(f1o + r0 + q * 4 + r, s1);
            atomicAdd(f2o + r0 + q * 4 + r, s2);
        }
    }
}

// ========== Kernel D: layer-2 attention + ELU + log_softmax -> out fp32 ==========
// grid 6144, block 64
__global__ void k_attn2(const int* __restrict__ cnt, const int* __restrict__ idxbuf,
                        const float* __restrict__ Wh2, const float* __restrict__ f1o,
                        const float* __restrict__ f2o, float* __restrict__ out){
    int i = blockIdx.x, l = threadIdx.x;
    int c = cnt[i];
    __shared__ int   sidx[CAP];
    __shared__ float sp[CAP];
    const int* src = idxbuf + (size_t)i * CAP;
    for (int e = l; e < c; e += 64) sidx[e] = src[e];
    __syncthreads();
    float f1i = f1o[i];
    float mx = -1e30f;
    for (int e = l; e < c; e += 64){
        float s = f1i + f2o[sidx[e]];
        s = s > 0.f ? s : LRELU_ALPHA * s;
        sp[e] = s;
        mx = fmaxf(mx, s);
    }
    for (int off = 32; off; off >>= 1) mx = fmaxf(mx, __shfl_xor(mx, off));
    __syncthreads();
    float ssum = 0.f;
    for (int e = l; e < c; e += 64){
        float p = __expf(sp[e] - mx);
        sp[e] = p;
        ssum += p;
    }
    for (int off = 32; off; off >>= 1) ssum += __shfl_xor(ssum, off);
    float inv = 1.f / ssum;
    __syncthreads();
    float acc = 0.f;
    if (l < NCLS){
        const float* wb = Wh2 + l;
        int e = 0;
        for (; e + 4 <= c; e += 4){
            int j0 = sidx[e], j1 = sidx[e+1], j2 = sidx[e+2], j3 = sidx[e+3];
            float v0 = wb[(size_t)j0 * NCLS];
            float v1 = wb[(size_t)j1 * NCLS];
            float v2 = wb[(size_t)j2 * NCLS];
            float v3 = wb[(size_t)j3 * NCLS];
            acc += sp[e]*v0 + sp[e+1]*v1 + sp[e+2]*v2 + sp[e+3]*v3;
        }
        for (; e < c; e++)
            acc += sp[e] * wb[(size_t)sidx[e] * NCLS];
        acc *= inv;
    }
    float o = (l < NCLS) ? (acc > 0.f ? acc : __expf(acc) - 1.f) : -1e30f;
    float m2 = o;
    for (int off = 32; off; off >>= 1) m2 = fmaxf(m2, __shfl_xor(m2, off));
    float ex = (l < NCLS) ? __expf(o - m2) : 0.f;
    for (int off = 32; off; off >>= 1) ex += __shfl_xor(ex, off);
    float res = o - m2 - logf(ex);
    if (l < NCLS) out[(size_t)i * NCLS + l] = res;
}

extern "C" void kernel_launch(void* const* d_in, const int* in_sizes, int n_in,
                              void* d_out, int out_size, void* d_ws, size_t ws_size,
                              hipStream_t stream) {
    const float* x   = (const float*)d_in[0];
    const float* adj = (const float*)d_in[1];
    const float* W   = (const float*)d_in[2];
    const float* a1  = (const float*)d_in[3];
    const float* a2  = (const float*)d_in[4];
    const float* Wo  = (const float*)d_in[5];
    const float* ao1 = (const float*)d_in[6];
    const float* ao2 = (const float*)d_in[7];
    float* out = (float*)d_out;

    char* ws = (char*)d_ws;
    int*      nbr_cnt = (int*)     (ws + 0);          //     24,576 B
    int*      nbr_idx = (int*)     (ws + 24576);      //  4,718,592 B
    uint16_t* Woth    = (uint16_t*)(ws + 4743168);    //     24,576 B
    uint16_t* Wotl    = (uint16_t*)(ws + 4767744);    //     24,576 B
    uint16_t* Wh1b    = (uint16_t*)(ws + 4792320);    //  3,145,728 B
    float*    f1      = (float*)   (ws + 7938048);    //     98,304 B
    float*    f2      = (float*)   (ws + 8036352);    //     98,304 B
    uint16_t* hch     = (uint16_t*)(ws + 8134656);    //  3,145,728 B
    uint16_t* hcl     = (uint16_t*)(ws + 11280384);   //  3,145,728 B
    float*    Wh2     = (float*)   (ws + 14426112);   //    983,040 B
    float*    f1o     = (float*)   (ws + 15409152);   //     24,576 B
    float*    f2o     = (float*)   (ws + 15433728);   //     24,576 B -> total ~15.5 MB

    hipLaunchKernelGGL(k_A,     dim3(6577),   dim3(256), 0, stream, adj, x, W, Wo, a1, a2,
                       nbr_cnt, nbr_idx, Woth, Wotl, Wh1b, f1, f2, f1o, f2o);
    hipLaunchKernelGGL(k_attn1, dim3(6144),   dim3(256), 0, stream, nbr_cnt, nbr_idx,
                       Wh1b, f1, f2, hch, hcl);
    hipLaunchKernelGGL(k_gemm2, dim3(192, 3), dim3(128), 0, stream, hch, hcl, Woth, Wotl,
                       ao1, ao2, Wh2, f1o, f2o);
    hipLaunchKernelGGL(k_attn2, dim3(6144),   dim3(64),  0, stream, nbr_cnt, nbr_idx,
                       Wh2, f1o, f2o, out);
}